// Round 14
// baseline (57.852 us; speedup 1.0000x reference)
//
#include <hip/hip_runtime.h>

#define H 1024
#define W 1024
#define NB 8
#define TY 8
#define NT 128              /* 2 waves per block */
#define BCOLS 512           /* cols per block */
#define WCOLS 256           /* cols per wave */
#define LW (WCOLS + 8)      /* 264: 4-col halo each side */

__global__ void ncc_zero(double* acc) { *acc = 0.0; }

__global__ void ncc_finalize(const double* __restrict__ acc, float* __restrict__ out) {
    out[0] = 1.0f - (float)(*acc * (1.0 / 8388608.0));  // 8*1024*1024 pixels
}

__global__ __launch_bounds__(NT) void ncc_main(
    const float* __restrict__ Jg,  // y_pred
    const float* __restrict__ Ig,  // y_true
    double* __restrict__ acc)
{
    __shared__ float vs[NT / 64][5][2][LW];   // [wave][quantity][slot][col]
    __shared__ double sred[NT / 64];

    const int b     = blockIdx.x;
    const int y0    = blockIdx.y * TY;
    const int xbase = blockIdx.z * BCOLS;
    const int t     = threadIdx.x;
    const int w     = t >> 6;
    const int lane  = t & 63;
    const int xw    = lane << 2;
    const int x0    = xbase + (w << 8) + xw;

    const float* __restrict__ Ib = Ig + (size_t)b * (H * W);
    const float* __restrict__ Jb = Jg + (size_t)b * (H * W);

    // halo: lanes 0..3 left halo cols, 4..7 right halo cols (one scalar col each)
    const int   wbase = xbase + (w << 8);
    const bool  isH   = (lane < 8);
    const int   hc    = (lane < 4) ? (wbase - 4 + lane) : (wbase + WCOLS + (lane - 4));
    const float mh    = (isH && (unsigned)hc < (unsigned)W) ? 1.0f : 0.0f;
    const int   hcc   = min(max(hc, 0), W - 1);
    const int   hslot = (lane < 4) ? lane : (WCOLS + lane);

    float sI[4]={0,0,0,0}, sJ[4]={0,0,0,0}, sII[4]={0,0,0,0}, sJJ[4]={0,0,0,0}, sIJ[4]={0,0,0,0};
    float hs0=0, hs1=0, hs2=0, hs3=0, hs4=0;

// load one row's own float4 (I and J) + halo scalars; mask by row validity
#define LOADROW(r4I, r4J, rhI, rhJ, mval, yy) do {                                  \
        const int   rr_ = (yy);                                                     \
        mval = ((unsigned)rr_ < (unsigned)H) ? 1.0f : 0.0f;                         \
        const int   rc_ = min(max(rr_, 0), H - 1);                                  \
        const float* pI_ = Ib + (size_t)rc_ * W;                                    \
        const float* pJ_ = Jb + (size_t)rc_ * W;                                    \
        r4I = *(const float4*)(pI_ + x0);                                           \
        r4J = *(const float4*)(pJ_ + x0);                                           \
        rhI = 0.f; rhJ = 0.f;                                                       \
        if (isH) { rhI = pI_[hcc]; rhJ = pJ_[hcc]; }                                \
    } while (0)

// slide window forward one row: add enter (e*, ema), subtract leave (l*, lms)
#define SLIDE(eI, eJ, ehI, ehJ, ema, lI, lJ, lhI, lhJ, lms) do {                    \
        const float fa0=eI.x*ema, fa1=eI.y*ema, fa2=eI.z*ema, fa3=eI.w*ema;         \
        const float ga0=eJ.x*ema, ga1=eJ.y*ema, ga2=eJ.z*ema, ga3=eJ.w*ema;         \
        const float fs0=lI.x*lms, fs1=lI.y*lms, fs2=lI.z*lms, fs3=lI.w*lms;         \
        const float gs0=lJ.x*lms, gs1=lJ.y*lms, gs2=lJ.z*lms, gs3=lJ.w*lms;         \
        sI[0] += fa0 - fs0; sI[1] += fa1 - fs1; sI[2] += fa2 - fs2; sI[3] += fa3 - fs3; \
        sJ[0] += ga0 - gs0; sJ[1] += ga1 - gs1; sJ[2] += ga2 - gs2; sJ[3] += ga3 - gs3; \
        sII[0] += fa0*fa0 - fs0*fs0; sII[1] += fa1*fa1 - fs1*fs1;                   \
        sII[2] += fa2*fa2 - fs2*fs2; sII[3] += fa3*fa3 - fs3*fs3;                   \
        sJJ[0] += ga0*ga0 - gs0*gs0; sJJ[1] += ga1*ga1 - gs1*gs1;                   \
        sJJ[2] += ga2*ga2 - gs2*gs2; sJJ[3] += ga3*ga3 - gs3*gs3;                   \
        sIJ[0] += fa0*ga0 - fs0*gs0; sIJ[1] += fa1*ga1 - fs1*gs1;                   \
        sIJ[2] += fa2*ga2 - fs2*gs2; sIJ[3] += fa3*ga3 - fs3*gs3;                   \
        const float hia = ehI * (ema * mh), hja = ehJ * (ema * mh);                 \
        const float his = lhI * (lms * mh), hjs = lhJ * (lms * mh);                 \
        hs0 += hia - his;                                                           \
        hs1 += hja - hjs;                                                           \
        hs2 += hia * hia - his * his;                                               \
        hs3 += hja * hja - hjs * hjs;                                               \
        hs4 += hia * hja - his * hjs;                                               \
    } while (0)

#define PUB(slot) do {                                                              \
        *(float4*)&vs[w][0][slot][4 + xw] = make_float4(sI[0],  sI[1],  sI[2],  sI[3]);  \
        *(float4*)&vs[w][1][slot][4 + xw] = make_float4(sJ[0],  sJ[1],  sJ[2],  sJ[3]);  \
        *(float4*)&vs[w][2][slot][4 + xw] = make_float4(sII[0], sII[1], sII[2], sII[3]); \
        *(float4*)&vs[w][3][slot][4 + xw] = make_float4(sJJ[0], sJJ[1], sJJ[2], sJJ[3]); \
        *(float4*)&vs[w][4][slot][4 + xw] = make_float4(sIJ[0], sIJ[1], sIJ[2], sIJ[3]); \
        if (isH) {                                                                  \
            vs[w][0][slot][hslot] = hs0; vs[w][1][slot][hslot] = hs1;               \
            vs[w][2][slot][hslot] = hs2; vs[w][3][slot][hslot] = hs3;               \
            vs[w][4][slot][hslot] = hs4;                                            \
        }                                                                           \
    } while (0)

#define HTAP(a, cg, T, o) do {                                                      \
        float s_ = a.x + a.y + a.z + a.w + cg.x + T;                                \
        o[0] = s_; s_ += cg.y - a.x;                                                \
        o[1] = s_; s_ += cg.z - a.y;                                                \
        o[2] = s_; s_ += cg.w - a.z;                                                \
        o[3] = s_;                                                                  \
    } while (0)

#define CCROW(A0,C0,A1,C1,A2,C2,A3,C3,A4,C4, TI,TJ,TII,TJJ,TIJ) do {                \
        float h0[4], h1[4], h2[4], h3[4], h4[4];                                    \
        HTAP(A0,C0,TI,h0); HTAP(A1,C1,TJ,h1); HTAP(A2,C2,TII,h2);                   \
        HTAP(A3,C3,TJJ,h3); HTAP(A4,C4,TIJ,h4);                                     \
        _Pragma("unroll")                                                           \
        for (int c = 0; c < 4; ++c) {                                               \
            const float uI    = h0[c] * inv;                                        \
            const float uJ    = h1[c] * inv;                                        \
            const float cross = h4[c] * inv - uI * uJ;                              \
            const float Iv    = h2[c] * inv - uI * uI;                              \
            const float Jv    = h3[c] * inv - uJ * uJ;                              \
            accv += cross * rsqrtf(fmaxf(Iv * Jv, 1e-7f));                          \
        }                                                                           \
    } while (0)

    // ---- init: fold rows y0-4 .. y0+4 -> window(y0), one row ahead in flight ----
    {
        float4 civ, cjv; float chi, chj, cm;
        LOADROW(civ, cjv, chi, chj, cm, y0 - 4);
        #pragma unroll 1
        for (int k = -4; k <= 4; ++k) {
            float4 niv, njv; float nhi, nhj, nm;
            LOADROW(niv, njv, nhi, nhj, nm, y0 + ((k < 4) ? (k + 1) : 4));
            const float fi0=civ.x*cm, fi1=civ.y*cm, fi2=civ.z*cm, fi3=civ.w*cm;
            const float fj0=cjv.x*cm, fj1=cjv.y*cm, fj2=cjv.z*cm, fj3=cjv.w*cm;
            sI[0]+=fi0; sI[1]+=fi1; sI[2]+=fi2; sI[3]+=fi3;
            sJ[0]+=fj0; sJ[1]+=fj1; sJ[2]+=fj2; sJ[3]+=fj3;
            sII[0]+=fi0*fi0; sII[1]+=fi1*fi1; sII[2]+=fi2*fi2; sII[3]+=fi3*fi3;
            sJJ[0]+=fj0*fj0; sJJ[1]+=fj1*fj1; sJJ[2]+=fj2*fj2; sJJ[3]+=fj3*fj3;
            sIJ[0]+=fi0*fj0; sIJ[1]+=fi1*fj1; sIJ[2]+=fi2*fj2; sIJ[3]+=fi3*fj3;
            const float mm = cm * mh;
            const float hi = chi * mm, hj = chj * mm;
            hs0 += hi; hs1 += hj; hs2 += hi*hi; hs3 += hj*hj; hs4 += hi*hj;
            civ = niv; cjv = njv; chi = nhi; chj = nhj; cm = nm;
        }
    }

    const float inv = 1.0f / 81.0f;
    float accv = 0.0f;

    // ---- prologue: T(y0), publish slot0; slide->window(y0+1); T(y0+1), publish slot1 ----
    float t0I, t0J, t0II, t0JJ, t0IJ, t1I, t1J, t1II, t1JJ, t1IJ;
    t0I  = sI[0]+sI[1]+sI[2]+sI[3];   t0J  = sJ[0]+sJ[1]+sJ[2]+sJ[3];
    t0II = sII[0]+sII[1]+sII[2]+sII[3]; t0JJ = sJJ[0]+sJJ[1]+sJJ[2]+sJJ[3];
    t0IJ = sIJ[0]+sIJ[1]+sIJ[2]+sIJ[3];
    PUB(0);
    asm volatile("" ::: "memory");
    {
        float4 eI, eJ, lI, lJ; float ehI, ehJ, ema, lhI, lhJ, lms;
        LOADROW(eI, eJ, ehI, ehJ, ema, y0 + 5);
        LOADROW(lI, lJ, lhI, lhJ, lms, y0 - 4);
        SLIDE(eI, eJ, ehI, ehJ, ema, lI, lJ, lhI, lhJ, lms);
    }
    t1I  = sI[0]+sI[1]+sI[2]+sI[3];   t1J  = sJ[0]+sJ[1]+sJ[2]+sJ[3];
    t1II = sII[0]+sII[1]+sII[2]+sII[3]; t1JJ = sJJ[0]+sJJ[1]+sJJ[2]+sJJ[3];
    t1IJ = sIJ[0]+sIJ[1]+sIJ[2]+sIJ[3];
    PUB(1);
    asm volatile("" ::: "memory");

    // distance-1 prefetch of the two enter rows for the first iteration
    float4 peAI, peAJ, peBI, peBJ; float peAhI, peAhJ, pmA, peBhI, peBhJ, pmB;
    LOADROW(peAI, peAJ, peAhI, peAhJ, pmA, y0 + 6);
    LOADROW(peBI, peBJ, peBhI, peBhJ, pmB, y0 + 7);

    // ---- main loop: 2 output rows per iteration ----
    #pragma unroll 1
    for (int k = 0; k < TY / 2; ++k) {
        const int yy = y0 + 2 * k;

        // leave row for slide 1 (L2/L3-resident: read 9 rows ago by this wave)
        float4 l0I, l0J; float l0hI, l0hJ, l0m;
        LOADROW(l0I, l0J, l0hI, l0hJ, l0m, yy - 3);

        // halos of window(yy) — published one full iteration ago
        float4 a0 = *(const float4*)&vs[w][0][0][xw], c0 = *(const float4*)&vs[w][0][0][xw + 8];
        float4 a1 = *(const float4*)&vs[w][1][0][xw], c1 = *(const float4*)&vs[w][1][0][xw + 8];
        float4 a2 = *(const float4*)&vs[w][2][0][xw], c2 = *(const float4*)&vs[w][2][0][xw + 8];
        float4 a3 = *(const float4*)&vs[w][3][0][xw], c3 = *(const float4*)&vs[w][3][0][xw + 8];
        float4 a4 = *(const float4*)&vs[w][4][0][xw], c4 = *(const float4*)&vs[w][4][0][xw + 8];
        asm volatile("" ::: "memory");

        // slide -> window(yy+2); snapshot T2; publish slot0
        SLIDE(peAI, peAJ, peAhI, peAhJ, pmA, l0I, l0J, l0hI, l0hJ, l0m);
        const float T2I  = sI[0]+sI[1]+sI[2]+sI[3];
        const float T2J  = sJ[0]+sJ[1]+sJ[2]+sJ[3];
        const float T2II = sII[0]+sII[1]+sII[2]+sII[3];
        const float T2JJ = sJJ[0]+sJJ[1]+sJJ[2]+sJJ[3];
        const float T2IJ = sIJ[0]+sIJ[1]+sIJ[2]+sIJ[3];
        PUB(0);
        asm volatile("" ::: "memory");

        // leave row for slide 2 (issued early; consumed after cc row yy)
        float4 l1I, l1J; float l1hI, l1hJ, l1m;
        LOADROW(l1I, l1J, l1hI, l1hJ, l1m, yy - 2);

        // cc for row yy (uses slot0 halos + T(yy) from last iter)
        CCROW(a0,c0,a1,c1,a2,c2,a3,c3,a4,c4, t0I,t0J,t0II,t0JJ,t0IJ);

        // halos of window(yy+1)
        float4 b0 = *(const float4*)&vs[w][0][1][xw], d0 = *(const float4*)&vs[w][0][1][xw + 8];
        float4 b1 = *(const float4*)&vs[w][1][1][xw], d1 = *(const float4*)&vs[w][1][1][xw + 8];
        float4 b2 = *(const float4*)&vs[w][2][1][xw], d2 = *(const float4*)&vs[w][2][1][xw + 8];
        float4 b3 = *(const float4*)&vs[w][3][1][xw], d3 = *(const float4*)&vs[w][3][1][xw + 8];
        float4 b4 = *(const float4*)&vs[w][4][1][xw], d4 = *(const float4*)&vs[w][4][1][xw + 8];
        asm volatile("" ::: "memory");

        // slide -> window(yy+3); snapshot T3; publish slot1
        SLIDE(peBI, peBJ, peBhI, peBhJ, pmB, l1I, l1J, l1hI, l1hJ, l1m);
        const float T3I  = sI[0]+sI[1]+sI[2]+sI[3];
        const float T3J  = sJ[0]+sJ[1]+sJ[2]+sJ[3];
        const float T3II = sII[0]+sII[1]+sII[2]+sII[3];
        const float T3JJ = sJJ[0]+sJJ[1]+sJJ[2]+sJJ[3];
        const float T3IJ = sIJ[0]+sIJ[1]+sIJ[2]+sIJ[3];
        PUB(1);
        asm volatile("" ::: "memory");

        // prefetch enter rows for next iteration (windows yy+4, yy+5)
        LOADROW(peAI, peAJ, peAhI, peAhJ, pmA, yy + 8);
        LOADROW(peBI, peBJ, peBhI, peBhJ, pmB, yy + 9);

        // cc for row yy+1 (uses slot1 halos + T(yy+1) from last iter)
        CCROW(b0,d0,b1,d1,b2,d2,b3,d3,b4,d4, t1I,t1J,t1II,t1JJ,t1IJ);

        // roll T snapshots forward
        t0I = T2I; t0J = T2J; t0II = T2II; t0JJ = T2JJ; t0IJ = T2IJ;
        t1I = T3I; t1J = T3J; t1II = T3II; t1JJ = T3JJ; t1IJ = T3IJ;
    }

#undef CCROW
#undef HTAP
#undef PUB
#undef SLIDE
#undef LOADROW

    // wave reduce (64 lanes) -> LDS -> one atomic per block (cold path)
    #pragma unroll
    for (int off = 32; off > 0; off >>= 1)
        accv += __shfl_down(accv, off);
    if (lane == 0)
        sred[w] = (double)accv;
    __syncthreads();
    if (t == 0) {
        double s = sred[0];
        #pragma unroll
        for (int q = 1; q < NT / 64; ++q) s += sred[q];
        atomicAdd(acc, s);
    }
}

extern "C" void kernel_launch(void* const* d_in, const int* in_sizes, int n_in,
                              void* d_out, int out_size, void* d_ws, size_t ws_size,
                              hipStream_t stream) {
    const float* y_pred = (const float*)d_in[0];  // Ji
    const float* y_true = (const float*)d_in[1];  // Ii
    float* out = (float*)d_out;
    double* accp = (double*)d_ws;

    ncc_zero<<<dim3(1), dim3(1), 0, stream>>>(accp);
    // 8 x 128 x 2 = 2048 blocks x 2 waves; 2 rows per iteration, dual LDS slots
    dim3 grid(NB, H / TY, W / BCOLS);
    ncc_main<<<grid, dim3(NT), 0, stream>>>(y_pred, y_true, accp);
    ncc_finalize<<<dim3(1), dim3(1), 0, stream>>>(accp, out);
}

// Round 15
// 54.014 us; speedup vs baseline: 1.0711x; 1.0711x over previous
//
#include <hip/hip_runtime.h>

#define H 1024
#define W 1024
#define NB 8
#define TY 8
#define NT 256
#define WCOLS 256           /* output cols per wave */
#define LW (WCOLS + 8)      /* 264: 4-col halo each side */

__global__ void ncc_zero(double* acc) { *acc = 0.0; }

__global__ void ncc_finalize(const double* __restrict__ acc, float* __restrict__ out) {
    out[0] = 1.0f - (float)(*acc * (1.0 / 8388608.0));  // 8*1024*1024 pixels
}

// pack 2 f32 -> u32 holding 2 bf16 (lo in [15:0], hi in [31:16]), RNE
__device__ __forceinline__ unsigned pk2(float lo, float hi) {
    unsigned r;
    asm("v_cvt_pk_bf16_f32 %0, %1, %2" : "=v"(r) : "v"(lo), "v"(hi));
    return r;
}
__device__ __forceinline__ float ulo(unsigned u) { return __uint_as_float(u << 16); }
__device__ __forceinline__ float uhi(unsigned u) { return __uint_as_float(u & 0xffff0000u); }

__global__ __launch_bounds__(NT) void ncc_main(
    const float* __restrict__ Jg,  // y_pred
    const float* __restrict__ Ig,  // y_true
    double* __restrict__ acc)
{
    __shared__ float vs[NT / 64][5][LW];   // wave-private vertical sums: I,J,II,JJ,IJ
    __shared__ double sred[NT / 64];

    const int b    = blockIdx.x;
    const int y0   = blockIdx.y * TY;
    const int t    = threadIdx.x;
    const int w    = t >> 6;
    const int lane = t & 63;
    const int xw   = lane << 2;
    const int x0   = (w << 8) + xw;

    const float* __restrict__ Ib = Ig + (size_t)b * (H * W);
    const float* __restrict__ Jb = Jg + (size_t)b * (H * W);

    // halo: lanes 0..3 maintain left halo cols, 4..7 right halo cols (1 scalar col each)
    const int   wbase = w << 8;
    const bool  isH   = (lane < 8);
    const int   hc    = (lane < 4) ? (wbase - 4 + lane) : (wbase + WCOLS + (lane - 4));
    const float mh    = (isH && (unsigned)hc < (unsigned)W) ? 1.0f : 0.0f;
    const int   hcc   = min(max(hc, 0), W - 1);
    const int   hslot = (lane < 4) ? lane : (WCOLS + lane);

    float sI[4]={0,0,0,0}, sJ[4]={0,0,0,0}, sII[4]={0,0,0,0}, sJJ[4]={0,0,0,0}, sIJ[4]={0,0,0,0};
    float hs0=0, hs1=0, hs2=0, hs3=0, hs4=0;

// declare a packed-row register set: {i01, i23, j01, j23, haloIJ}
#define RDECL(n) unsigned n##0, n##1, n##2, n##3, n##4;

// load row yy (clamped addr, validity-masked values), quantize to bf16-packed set
#define LOADPACK(dst, yy) do {                                                      \
        const int   r_  = (yy);                                                     \
        const float m_  = ((unsigned)r_ < (unsigned)H) ? 1.0f : 0.0f;               \
        const int   rc_ = min(max(r_, 0), H - 1);                                   \
        const float4 iv_ = *(const float4*)(Ib + (size_t)rc_ * W + x0);             \
        const float4 jv_ = *(const float4*)(Jb + (size_t)rc_ * W + x0);             \
        float ih_ = 0.f, jh_ = 0.f;                                                 \
        if (isH) { ih_ = Ib[(size_t)rc_ * W + hcc]; jh_ = Jb[(size_t)rc_ * W + hcc]; } \
        dst##0 = pk2(iv_.x * m_, iv_.y * m_);                                       \
        dst##1 = pk2(iv_.z * m_, iv_.w * m_);                                       \
        dst##2 = pk2(jv_.x * m_, jv_.y * m_);                                       \
        dst##3 = pk2(jv_.z * m_, jv_.w * m_);                                       \
        dst##4 = pk2(ih_ * (m_ * mh), jh_ * (m_ * mh));                             \
    } while (0)

// fold a packed row into the running sums with sign SG (+1 enter / -1 leave).
// Identical packed value on enter and leave -> exact cancellation, no drift.
#define FOLD(src, SG) do {                                                          \
        const float i0_=ulo(src##0), i1_=uhi(src##0), i2_=ulo(src##1), i3_=uhi(src##1); \
        const float j0_=ulo(src##2), j1_=uhi(src##2), j2_=ulo(src##3), j3_=uhi(src##3); \
        const float hA_=ulo(src##4), hB_=uhi(src##4);                               \
        sI[0]=fmaf(SG,i0_,sI[0]); sI[1]=fmaf(SG,i1_,sI[1]);                         \
        sI[2]=fmaf(SG,i2_,sI[2]); sI[3]=fmaf(SG,i3_,sI[3]);                         \
        sJ[0]=fmaf(SG,j0_,sJ[0]); sJ[1]=fmaf(SG,j1_,sJ[1]);                         \
        sJ[2]=fmaf(SG,j2_,sJ[2]); sJ[3]=fmaf(SG,j3_,sJ[3]);                         \
        sII[0]=fmaf(SG,i0_*i0_,sII[0]); sII[1]=fmaf(SG,i1_*i1_,sII[1]);             \
        sII[2]=fmaf(SG,i2_*i2_,sII[2]); sII[3]=fmaf(SG,i3_*i3_,sII[3]);             \
        sJJ[0]=fmaf(SG,j0_*j0_,sJJ[0]); sJJ[1]=fmaf(SG,j1_*j1_,sJJ[1]);             \
        sJJ[2]=fmaf(SG,j2_*j2_,sJJ[2]); sJJ[3]=fmaf(SG,j3_*j3_,sJJ[3]);             \
        sIJ[0]=fmaf(SG,i0_*j0_,sIJ[0]); sIJ[1]=fmaf(SG,i1_*j1_,sIJ[1]);             \
        sIJ[2]=fmaf(SG,i2_*j2_,sIJ[2]); sIJ[3]=fmaf(SG,i3_*j3_,sIJ[3]);             \
        hs0=fmaf(SG,hA_,hs0); hs1=fmaf(SG,hB_,hs1);                                 \
        hs2=fmaf(SG,hA_*hA_,hs2); hs3=fmaf(SG,hB_*hB_,hs3);                         \
        hs4=fmaf(SG,hA_*hB_,hs4);                                                   \
    } while (0)

#define PUB() do {                                                                  \
        *(float4*)&vs[w][0][4 + xw] = make_float4(sI[0],  sI[1],  sI[2],  sI[3]);   \
        *(float4*)&vs[w][1][4 + xw] = make_float4(sJ[0],  sJ[1],  sJ[2],  sJ[3]);   \
        *(float4*)&vs[w][2][4 + xw] = make_float4(sII[0], sII[1], sII[2], sII[3]);  \
        *(float4*)&vs[w][3][4 + xw] = make_float4(sJJ[0], sJJ[1], sJJ[2], sJJ[3]);  \
        *(float4*)&vs[w][4][4 + xw] = make_float4(sIJ[0], sIJ[1], sIJ[2], sIJ[3]);  \
        if (isH) {                                                                  \
            vs[w][0][hslot] = hs0; vs[w][1][hslot] = hs1; vs[w][2][hslot] = hs2;    \
            vs[w][3][hslot] = hs3; vs[w][4][hslot] = hs4;                           \
        }                                                                           \
    } while (0)

#define HTAP(a, cg, T, o) do {                                                      \
        float s_ = a.x + a.y + a.z + a.w + cg.x + T;                                \
        o[0] = s_; s_ += cg.y - a.x;                                                \
        o[1] = s_; s_ += cg.z - a.y;                                                \
        o[2] = s_; s_ += cg.w - a.z;                                                \
        o[3] = s_;                                                                  \
    } while (0)

    // ---- ring: the 9 init rows, packed bf16 in registers (write-once, read-once) ----
    RDECL(q0) RDECL(q1) RDECL(q2) RDECL(q3) RDECL(q4) RDECL(q5) RDECL(q6) RDECL(q7)
    RDECL(q8)
    // issue all 9 row loads first (batched, deep MLP), then fold
    LOADPACK(q0, y0 - 4); LOADPACK(q1, y0 - 3); LOADPACK(q2, y0 - 2);
    LOADPACK(q3, y0 - 1); LOADPACK(q4, y0    ); LOADPACK(q5, y0 + 1);
    LOADPACK(q6, y0 + 2); LOADPACK(q7, y0 + 3); LOADPACK(q8, y0 + 4);
    FOLD(q0, 1.0f); FOLD(q1, 1.0f); FOLD(q2, 1.0f); FOLD(q3, 1.0f); FOLD(q4, 1.0f);
    FOLD(q5, 1.0f); FOLD(q6, 1.0f); FOLD(q7, 1.0f); FOLD(q8, 1.0f);
    // q8 (row y0+4) never leaves within this strip; its regs die here.

    // ---- prologue: publish window(y0); prefetch enter rows y0+5 (A), y0+6 (B) ----
    PUB();
    asm volatile("" ::: "memory");
    RDECL(pA) RDECL(pB)
    LOADPACK(pA, y0 + 5);
    LOADPACK(pB, y0 + 6);

    const float inv = 1.0f / 81.0f;
    float accv = 0.0f;

#define CCROW(TI, TJ, TII, TJJ, TIJ) do {                                           \
        float h0[4], h1[4], h2[4], h3[4], h4[4];                                    \
        HTAP(a0_, c0_, TI, h0); HTAP(a1_, c1_, TJ, h1); HTAP(a2_, c2_, TII, h2);    \
        HTAP(a3_, c3_, TJJ, h3); HTAP(a4_, c4_, TIJ, h4);                           \
        _Pragma("unroll")                                                           \
        for (int c = 0; c < 4; ++c) {                                               \
            const float uI    = h0[c] * inv;                                        \
            const float uJ    = h1[c] * inv;                                        \
            const float cross = h4[c] * inv - uI * uJ;                              \
            const float Iv    = h2[c] * inv - uI * uI;                              \
            const float Jv    = h3[c] * inv - uJ * uJ;                              \
            accv += cross * rsqrtf(fmaxf(Iv * Jv, 1e-7f));                          \
        }                                                                           \
    } while (0)

#define HALO_READ()                                                                        \
        float4 a0_ = *(const float4*)&vs[w][0][xw], c0_ = *(const float4*)&vs[w][0][xw + 8]; \
        float4 a1_ = *(const float4*)&vs[w][1][xw], c1_ = *(const float4*)&vs[w][1][xw + 8]; \
        float4 a2_ = *(const float4*)&vs[w][2][xw], c2_ = *(const float4*)&vs[w][2][xw + 8]; \
        float4 a3_ = *(const float4*)&vs[w][3][xw], c3_ = *(const float4*)&vs[w][3][xw + 8]; \
        float4 a4_ = *(const float4*)&vs[w][4][xw], c4_ = *(const float4*)&vs[w][4][xw + 8];

// full iteration k (k = 0..6): halo-read(y0+k) -> T -> slide(leave=ring k, enter=P)
// -> publish(y0+k+1) -> refill P (rows beyond strip are DCE'd if never consumed)
#define ITER(k, P, RF) do {                                                         \
        HALO_READ();                                                                \
        asm volatile("" ::: "memory");                                              \
        const float T0 = sI[0]  + sI[1]  + sI[2]  + sI[3];                          \
        const float T1 = sJ[0]  + sJ[1]  + sJ[2]  + sJ[3];                          \
        const float T2 = sII[0] + sII[1] + sII[2] + sII[3];                         \
        const float T3 = sJJ[0] + sJJ[1] + sJJ[2] + sJJ[3];                         \
        const float T4 = sIJ[0] + sIJ[1] + sIJ[2] + sIJ[3];                         \
        FOLD(q##k, -1.0f);                                                          \
        FOLD(P, 1.0f);                                                              \
        PUB();                                                                      \
        asm volatile("" ::: "memory");                                              \
        RF;                                                                         \
        CCROW(T0, T1, T2, T3, T4);                                                  \
    } while (0)

    ITER(0, pA, LOADPACK(pA, y0 + 7));
    ITER(1, pB, LOADPACK(pB, y0 + 8));
    ITER(2, pA, LOADPACK(pA, y0 + 9));
    ITER(3, pB, LOADPACK(pB, y0 + 10));
    ITER(4, pA, LOADPACK(pA, y0 + 11));
    ITER(5, pB, LOADPACK(pB, y0 + 12));
    ITER(6, pA, (void)0);
    // last row: no slide, no publish needed — just read halos + cc
    {
        HALO_READ();
        asm volatile("" ::: "memory");
        const float T0 = sI[0]  + sI[1]  + sI[2]  + sI[3];
        const float T1 = sJ[0]  + sJ[1]  + sJ[2]  + sJ[3];
        const float T2 = sII[0] + sII[1] + sII[2] + sII[3];
        const float T3 = sJJ[0] + sJJ[1] + sJJ[2] + sJJ[3];
        const float T4 = sIJ[0] + sIJ[1] + sIJ[2] + sIJ[3];
        CCROW(T0, T1, T2, T3, T4);
    }

#undef ITER
#undef HALO_READ
#undef CCROW
#undef HTAP
#undef PUB
#undef FOLD
#undef LOADPACK
#undef RDECL

    // wave reduce (64 lanes) -> LDS -> one atomic per block (cold path)
    #pragma unroll
    for (int off = 32; off > 0; off >>= 1)
        accv += __shfl_down(accv, off);
    if (lane == 0)
        sred[w] = (double)accv;
    __syncthreads();
    if (t == 0) {
        double s = sred[0];
        #pragma unroll
        for (int q = 1; q < NT / 64; ++q) s += sred[q];
        atomicAdd(acc, s);
    }
}

extern "C" void kernel_launch(void* const* d_in, const int* in_sizes, int n_in,
                              void* d_out, int out_size, void* d_ws, size_t ws_size,
                              hipStream_t stream) {
    const float* y_pred = (const float*)d_in[0];  // Ji
    const float* y_true = (const float*)d_in[1];  // Ii
    float* out = (float*)d_out;
    double* accp = (double*)d_ws;

    ncc_zero<<<dim3(1), dim3(1), 0, stream>>>(accp);
    dim3 grid(NB, H / TY);  // 8 x 128 = 1024 blocks; bf16 register ring, no leave loads
    ncc_main<<<grid, dim3(NT), 0, stream>>>(y_pred, y_true, accp);
    ncc_finalize<<<dim3(1), dim3(1), 0, stream>>>(accp, out);
}